// Round 1
// baseline (293.465 us; speedup 1.0000x reference)
//
#include <hip/hip_runtime.h>
#include <float.h>

// HaloAttn: x(4,128,128,128) f32 -> out(4,128,128,128) f32
// BS=8, HS=3, WIN=14, NH=8, DQK=DV=16, SCALE=0.25
//
// Pipeline:
//  k1: gemm_xbt  y_q = x @ q_w^T -> d_out (65536 x 128), y_kv = x @ kv_w^T -> d_ws (65536 x 256)
//  k2: halo_attn per (block,batch): q from d_out, kv windows from d_ws, writes attn-out over q slot
//  k3: gemm_xbt  d_out = d_out @ proj_w^T + proj_b (in-place, row-block safe)

// ---------------------------------------------------------------------------
// GEMM: C[tile 128x128] = A(M x 128) @ B^T (+bias). BK=32, 8x8 per thread.
// A/C intentionally NOT __restrict__ (kernel-3 runs in place on d_out).
__global__ __launch_bounds__(256) void gemm_xbt(
    const float* A, int lda,
    const float* __restrict__ Bq, const float* __restrict__ Bkv,
    const float* __restrict__ bias,
    float* Cq, int ldcq, float* Ckv, int ldckv)
{
    __shared__ float aT[32][132];   // transposed: aT[k][row]
    __shared__ float bT[32][132];   // transposed: bT[k][col]

    const int t  = threadIdx.x;
    const int mt = blockIdx.x, nt = blockIdx.y;

    const float* Bt = (nt == 0) ? Bq : (Bkv + (size_t)(nt - 1) * (128 * 128));
    float*       C  = (nt == 0) ? Cq : Ckv;
    const int    ldc  = (nt == 0) ? ldcq : ldckv;
    const int    col0 = (nt == 0) ? 0 : (nt - 1) * 128;
    const int    row0 = mt * 128;

    const int tr = t >> 4, tc = t & 15;

    float acc[8][8];
#pragma unroll
    for (int i = 0; i < 8; ++i)
#pragma unroll
        for (int j = 0; j < 8; ++j) acc[i][j] = 0.f;

#pragma unroll 1
    for (int k0 = 0; k0 < 128; k0 += 32) {
#pragma unroll
        for (int i = t; i < 1024; i += 256) {         // 128 rows x 8 f4-chunks
            int r = i >> 3, k4 = i & 7;
            const float4 v = *(const float4*)(A + (size_t)(row0 + r) * lda + k0 + k4 * 4);
            aT[k4*4+0][r] = v.x; aT[k4*4+1][r] = v.y;
            aT[k4*4+2][r] = v.z; aT[k4*4+3][r] = v.w;
        }
#pragma unroll
        for (int i = t; i < 1024; i += 256) {
            int r = i >> 3, k4 = i & 7;
            const float4 v = *(const float4*)(Bt + (size_t)r * 128 + k0 + k4 * 4);
            bT[k4*4+0][r] = v.x; bT[k4*4+1][r] = v.y;
            bT[k4*4+2][r] = v.z; bT[k4*4+3][r] = v.w;
        }
        __syncthreads();
#pragma unroll
        for (int k = 0; k < 32; ++k) {
            const float4 a0 = *(const float4*)&aT[k][tr * 4];
            const float4 a1 = *(const float4*)&aT[k][64 + tr * 4];
            const float4 b0 = *(const float4*)&bT[k][tc * 4];
            const float4 b1 = *(const float4*)&bT[k][64 + tc * 4];
            const float av[8] = {a0.x,a0.y,a0.z,a0.w,a1.x,a1.y,a1.z,a1.w};
            const float bv[8] = {b0.x,b0.y,b0.z,b0.w,b1.x,b1.y,b1.z,b1.w};
#pragma unroll
            for (int i = 0; i < 8; ++i)
#pragma unroll
                for (int j = 0; j < 8; ++j)
                    acc[i][j] = fmaf(av[i], bv[j], acc[i][j]);
        }
        __syncthreads();
    }

#pragma unroll
    for (int ih = 0; ih < 2; ++ih)
#pragma unroll
    for (int ii = 0; ii < 4; ++ii) {
        const int r = row0 + ih * 64 + tr * 4 + ii;
#pragma unroll
        for (int jh = 0; jh < 2; ++jh) {
            const int c = col0 + jh * 64 + tc * 4;
            float4 v;
            v.x = acc[ih*4+ii][jh*4+0]; v.y = acc[ih*4+ii][jh*4+1];
            v.z = acc[ih*4+ii][jh*4+2]; v.w = acc[ih*4+ii][jh*4+3];
            if (bias) {
                const int cb = (jh * 64 + tc * 4);
                v.x += bias[cb]; v.y += bias[cb+1]; v.z += bias[cb+2]; v.w += bias[cb+3];
            }
            *(float4*)(C + (size_t)r * ldc + c) = v;
        }
    }
}

// ---------------------------------------------------------------------------
// Attention. grid(256 blocks, 4 batch), 256 threads.
// qkv: q in d_out (pix,128); kv in d_ws (pix,256) channel c: head h -> k: h*32+d, v: h*32+16+d
__global__ __launch_bounds__(256) void halo_attn(
    float* qout,                      // d_out: q in, attn-out out (65536 x 128)
    const float* __restrict__ kv,     // d_ws: (65536 x 256)
    const float* __restrict__ pos_table)  // (729, 8)
{
    __shared__ float kw[196][20];
    __shared__ float vw[196][20];
    __shared__ float bias_l[441];

    const int t  = threadIdx.x;
    const int bi = blockIdx.x, b = blockIdx.y;
    const int by = bi >> 4, bx = bi & 15;

    const int qi = t >> 2, quarter = t & 3;
    const int qy = qi >> 3, qx = qi & 7;
    const int py = by * 8 + qy, px = bx * 8 + qx;
    float* pixq = qout + (((size_t)b * 128 + py) * 128 + px) * 128;

    // staging coords (threads 0..195 stage one window position each)
    const int sy = t / 14, sx = t % 14;
    const int ay = by * 8 + sy - 3, ax = bx * 8 + sx - 3;
    const bool svalid = ((unsigned)ay < 128u) && ((unsigned)ax < 128u) && (t < 196);
    const float* ksrc = kv + (((size_t)b * 128 + ay) * 128 + ax) * 256;

    const int by8 = by * 8 - 3, bx8 = bx * 8 - 3;

#pragma unroll 1
    for (int h = 0; h < 8; ++h) {
        for (int i = t; i < 441; i += 256)
            bias_l[i] = pos_table[((i / 21 + 3) * 27 + (i % 21) + 3) * 8 + h];
        if (t < 196) {
            const float* s = ksrc + h * 32;
            const float4 z = make_float4(0.f, 0.f, 0.f, 0.f);
#pragma unroll
            for (int c = 0; c < 4; ++c)
                *(float4*)&kw[t][c * 4] = svalid ? *(const float4*)(s + c * 4) : z;
#pragma unroll
            for (int c = 0; c < 4; ++c)
                *(float4*)&vw[t][c * 4] = svalid ? *(const float4*)(s + 16 + c * 4) : z;
        }
        __syncthreads();

        // q row into registers (4 lanes of a query read the same 16 floats)
        float q[16];
        {
            const float* qs = pixq + h * 16;
#pragma unroll
            for (int c = 0; c < 4; ++c) {
                const float4 v = *(const float4*)(qs + c * 4);
                q[c*4+0] = v.x; q[c*4+1] = v.y; q[c*4+2] = v.z; q[c*4+3] = v.w;
            }
        }

        float p[49];
        float m = -FLT_MAX;
#pragma unroll
        for (int j = 0; j < 49; ++j) {
            const int kj = quarter + 4 * j;
            const float4 k0 = *(const float4*)&kw[kj][0];
            const float4 k1 = *(const float4*)&kw[kj][4];
            const float4 k2 = *(const float4*)&kw[kj][8];
            const float4 k3 = *(const float4*)&kw[kj][12];
            float d = q[0] * k0.x;
            d = fmaf(q[1],  k0.y, d); d = fmaf(q[2],  k0.z, d); d = fmaf(q[3],  k0.w, d);
            d = fmaf(q[4],  k1.x, d); d = fmaf(q[5],  k1.y, d); d = fmaf(q[6],  k1.z, d);
            d = fmaf(q[7],  k1.w, d); d = fmaf(q[8],  k2.x, d); d = fmaf(q[9],  k2.y, d);
            d = fmaf(q[10], k2.z, d); d = fmaf(q[11], k2.w, d); d = fmaf(q[12], k3.x, d);
            d = fmaf(q[13], k3.y, d); d = fmaf(q[14], k3.z, d); d = fmaf(q[15], k3.w, d);
            const int ky = kj / 14, kx = kj % 14;
            const int ayk = by8 + ky, axk = bx8 + kx;
            const bool valid = ((unsigned)ayk < 128u) && ((unsigned)axk < 128u);
            const float bsv = bias_l[(qy + 13 - ky) * 21 + (qx + 13 - kx)];
            const float logit = valid ? fmaf(d, 0.25f, bsv) : -1e30f;
            p[j] = logit;
            m = fmaxf(m, logit);
        }
        m = fmaxf(m, __shfl_xor(m, 1));
        m = fmaxf(m, __shfl_xor(m, 2));

        float s = 0.f;
#pragma unroll
        for (int j = 0; j < 49; ++j) { p[j] = __expf(p[j] - m); s += p[j]; }
        s += __shfl_xor(s, 1);
        s += __shfl_xor(s, 2);
        const float inv = 1.0f / s;

        float acc[16];
#pragma unroll
        for (int d = 0; d < 16; ++d) acc[d] = 0.f;
#pragma unroll
        for (int j = 0; j < 49; ++j) {
            const int kj = quarter + 4 * j;
            const float pj = p[j];
            const float4 v0 = *(const float4*)&vw[kj][0];
            const float4 v1 = *(const float4*)&vw[kj][4];
            const float4 v2 = *(const float4*)&vw[kj][8];
            const float4 v3 = *(const float4*)&vw[kj][12];
            acc[0]  = fmaf(pj, v0.x, acc[0]);  acc[1]  = fmaf(pj, v0.y, acc[1]);
            acc[2]  = fmaf(pj, v0.z, acc[2]);  acc[3]  = fmaf(pj, v0.w, acc[3]);
            acc[4]  = fmaf(pj, v1.x, acc[4]);  acc[5]  = fmaf(pj, v1.y, acc[5]);
            acc[6]  = fmaf(pj, v1.z, acc[6]);  acc[7]  = fmaf(pj, v1.w, acc[7]);
            acc[8]  = fmaf(pj, v2.x, acc[8]);  acc[9]  = fmaf(pj, v2.y, acc[9]);
            acc[10] = fmaf(pj, v2.z, acc[10]); acc[11] = fmaf(pj, v2.w, acc[11]);
            acc[12] = fmaf(pj, v3.x, acc[12]); acc[13] = fmaf(pj, v3.y, acc[13]);
            acc[14] = fmaf(pj, v3.z, acc[14]); acc[15] = fmaf(pj, v3.w, acc[15]);
        }
#pragma unroll
        for (int d = 0; d < 16; ++d) {
            acc[d] += __shfl_xor(acc[d], 1);
            acc[d] += __shfl_xor(acc[d], 2);
        }
        __syncthreads();   // all kw/vw reads done before next head's staging

        float4 o;
        o.x = acc[quarter*4+0] * inv; o.y = acc[quarter*4+1] * inv;
        o.z = acc[quarter*4+2] * inv; o.w = acc[quarter*4+3] * inv;
        *(float4*)(pixq + h * 16 + quarter * 4) = o;   // overwrite own q slot
    }
}

// ---------------------------------------------------------------------------
extern "C" void kernel_launch(void* const* d_in, const int* in_sizes, int n_in,
                              void* d_out, int out_size, void* d_ws, size_t ws_size,
                              hipStream_t stream) {
    const float* x      = (const float*)d_in[0];
    const float* q_w    = (const float*)d_in[1];
    const float* kv_w   = (const float*)d_in[2];
    const float* pt     = (const float*)d_in[3];
    const float* proj_w = (const float*)d_in[4];
    const float* proj_b = (const float*)d_in[5];
    float* out = (float*)d_out;
    float* ykv = (float*)d_ws;   // (65536, 256) kv projections, 64 MB

    const dim3 blk(256);
    // k1: q -> d_out (ldc 128), kv -> ws (ldc 256)
    gemm_xbt<<<dim3(512, 3), blk, 0, stream>>>(x, 128, q_w, kv_w, nullptr,
                                               out, 128, ykv, 256);
    // k2: attention, overwrites q slots of d_out with attn output
    halo_attn<<<dim3(256, 4), blk, 0, stream>>>(out, ykv, pt);
    // k3: d_out = d_out @ proj_w^T + proj_b (in-place, row-block safe)
    gemm_xbt<<<dim3(512, 1), blk, 0, stream>>>(out, 128, proj_w, nullptr, proj_b,
                                               out, 128, nullptr, 128);
}

// Round 2
// 253.167 us; speedup vs baseline: 1.1592x; 1.1592x over previous
//
#include <hip/hip_runtime.h>
#include <float.h>

// HaloAttn: x(4,128,128,128) f32 -> out(4,128,128,128) f32
// BS=8, HS=3, WIN=14, NH=8, DQK=DV=16, SCALE=0.25
//
// k1: gemm_xbt  y_q = x @ q_w^T -> d_out, y_kv = x @ kv_w^T -> d_ws
// k2: halo_attn fused QK->exp->PV (no max-sub; softmax shift-invariant, logits bounded)
// k3: gemm_xbt  d_out = d_out @ proj_w^T + proj_b (in place)

// ---------------------------------------------------------------------------
__global__ __launch_bounds__(256) void gemm_xbt(
    const float* A, int lda,
    const float* __restrict__ Bq, const float* __restrict__ Bkv,
    const float* __restrict__ bias,
    float* Cq, int ldcq, float* Ckv, int ldckv)
{
    __shared__ float aT[32][132];
    __shared__ float bT[32][132];

    const int t  = threadIdx.x;
    const int mt = blockIdx.x, nt = blockIdx.y;

    const float* Bt = (nt == 0) ? Bq : (Bkv + (size_t)(nt - 1) * (128 * 128));
    float*       C  = (nt == 0) ? Cq : Ckv;
    const int    ldc  = (nt == 0) ? ldcq : ldckv;
    const int    col0 = (nt == 0) ? 0 : (nt - 1) * 128;
    const int    row0 = mt * 128;

    const int tr = t >> 4, tc = t & 15;

    float acc[8][8];
#pragma unroll
    for (int i = 0; i < 8; ++i)
#pragma unroll
        for (int j = 0; j < 8; ++j) acc[i][j] = 0.f;

#pragma unroll 1
    for (int k0 = 0; k0 < 128; k0 += 32) {
#pragma unroll
        for (int i = t; i < 1024; i += 256) {
            int r = i >> 3, k4 = i & 7;
            const float4 v = *(const float4*)(A + (size_t)(row0 + r) * lda + k0 + k4 * 4);
            aT[k4*4+0][r] = v.x; aT[k4*4+1][r] = v.y;
            aT[k4*4+2][r] = v.z; aT[k4*4+3][r] = v.w;
        }
#pragma unroll
        for (int i = t; i < 1024; i += 256) {
            int r = i >> 3, k4 = i & 7;
            const float4 v = *(const float4*)(Bt + (size_t)r * 128 + k0 + k4 * 4);
            bT[k4*4+0][r] = v.x; bT[k4*4+1][r] = v.y;
            bT[k4*4+2][r] = v.z; bT[k4*4+3][r] = v.w;
        }
        __syncthreads();
#pragma unroll
        for (int k = 0; k < 32; ++k) {
            const float4 a0 = *(const float4*)&aT[k][tr * 4];
            const float4 a1 = *(const float4*)&aT[k][64 + tr * 4];
            const float4 b0 = *(const float4*)&bT[k][tc * 4];
            const float4 b1 = *(const float4*)&bT[k][64 + tc * 4];
            const float av[8] = {a0.x,a0.y,a0.z,a0.w,a1.x,a1.y,a1.z,a1.w};
            const float bv[8] = {b0.x,b0.y,b0.z,b0.w,b1.x,b1.y,b1.z,b1.w};
#pragma unroll
            for (int i = 0; i < 8; ++i)
#pragma unroll
                for (int j = 0; j < 8; ++j)
                    acc[i][j] = fmaf(av[i], bv[j], acc[i][j]);
        }
        __syncthreads();
    }

#pragma unroll
    for (int ih = 0; ih < 2; ++ih)
#pragma unroll
    for (int ii = 0; ii < 4; ++ii) {
        const int r = row0 + ih * 64 + tr * 4 + ii;
#pragma unroll
        for (int jh = 0; jh < 2; ++jh) {
            const int c = col0 + jh * 64 + tc * 4;
            float4 v;
            v.x = acc[ih*4+ii][jh*4+0]; v.y = acc[ih*4+ii][jh*4+1];
            v.z = acc[ih*4+ii][jh*4+2]; v.w = acc[ih*4+ii][jh*4+3];
            if (bias) {
                const int cb = (jh * 64 + tc * 4);
                v.x += bias[cb]; v.y += bias[cb+1]; v.z += bias[cb+2]; v.w += bias[cb+3];
            }
            *(float4*)(C + (size_t)r * ldc + c) = v;
        }
    }
}

// ---------------------------------------------------------------------------
// Fused halo attention. grid(256 sp-blocks, 4 batch, 2 head-groups), 256 thr.
// Wave = one head (hl = t>>6). Lane: qg = (t&63)>>2 (4 queries), quarter = t&3
// (keys quarter+4j). K/V staged in 2 chunks of 98 keys, XOR-swizzled quads.
// Single pass: p = exp(logit) without max-sub (logits bounded, mask -> p=0),
// accumulate sum and p*V on the fly; divide at the end.
__global__ __launch_bounds__(256, 2) void halo_attn(
    float* qout,                          // q in, attn-out out (65536 x 128)
    const float* __restrict__ kv,         // (65536 x 256)
    const float* __restrict__ pos_table)  // (729, 8)
{
    __shared__ float4 kw[4][98][4];   // [head][key][quad], quad XOR-swizzled
    __shared__ float4 vw[4][98][4];
    __shared__ float  bias_l[4][441];

    const int t  = threadIdx.x;
    const int bi = blockIdx.x, b = blockIdx.y, hg = blockIdx.z;
    const int by = bi >> 4, bx = bi & 15;
    const int hl = t >> 6;                 // head within group == wave id
    const int head = hg * 4 + hl;
    const int l  = t & 63;
    const int qg = l >> 2, quarter = l & 3;
    const int by8 = by * 8 - 3, bx8 = bx * 8 - 3;

    // ---- load my 4 queries into registers; remember output pointers
    float qreg[4][16];
    float* qbase[4];
    int qoff[4];
#pragma unroll
    for (int qq = 0; qq < 4; ++qq) {
        const int q  = qg * 4 + qq;
        const int qy = q >> 3, qx = q & 7;
        qoff[qq] = qy * 21 + qx;
        float* p = qout + (((size_t)b * 128 + by * 8 + qy) * 128 + bx * 8 + qx) * 128
                 + head * 16;
        qbase[qq] = p;
#pragma unroll
        for (int c = 0; c < 4; ++c) {
            const float4 v = *(const float4*)(p + c * 4);
            qreg[qq][c*4+0] = v.x; qreg[qq][c*4+1] = v.y;
            qreg[qq][c*4+2] = v.z; qreg[qq][c*4+3] = v.w;
        }
    }

    // ---- stage bias for the 4 heads of this group
    for (int i = t; i < 1764; i += 256) {
        const int hh = i / 441, r = i - hh * 441;
        const int ry = r / 21, rx = r - ry * 21;
        bias_l[hh][r] = pos_table[((ry + 3) * 27 + rx + 3) * 8 + hg * 4 + hh];
    }

    float acc[4][16];
    float sum[4] = {0.f, 0.f, 0.f, 0.f};
#pragma unroll
    for (int qq = 0; qq < 4; ++qq)
#pragma unroll
        for (int d = 0; d < 16; ++d) acc[qq][d] = 0.f;

#pragma unroll 1
    for (int c = 0; c < 2; ++c) {
        const int kb = c * 98;
        // ---- stage chunk: 98 window rows x 4 heads (k 64B + v 64B each)
        for (int i = t; i < 392; i += 256) {
            const int h = i & 3, row = i >> 2;
            const int grow = kb + row;
            const int wy = grow / 14, wx = grow - wy * 14;
            const int ay = by * 8 + wy - 3, ax = bx * 8 + wx - 3;
            const bool sval = ((unsigned)ay < 128u) && ((unsigned)ax < 128u);
            const float4* s = (const float4*)(kv + (((size_t)b * 128 + ay) * 128 + ax) * 256
                                              + (hg * 4 + h) * 32);
            const int sw = ((row >> 1 ^ row >> 2) & 1) << 1;
            const float4 z = make_float4(0.f, 0.f, 0.f, 0.f);
#pragma unroll
            for (int c4 = 0; c4 < 4; ++c4) {
                kw[h][row][c4 ^ sw] = sval ? s[c4]     : z;
                vw[h][row][c4 ^ sw] = sval ? s[4 + c4] : z;
            }
        }
        __syncthreads();

        // ---- fused QK -> exp -> PV over this chunk
#pragma unroll 2
        for (int j = 0; j < 25; ++j) {
            const int kj   = quarter + 4 * j;
            const bool jv  = kj < 98;
            const int kjc  = jv ? kj : 97;
            const int grow = kb + kjc;
            const int wy = grow / 14, wx = grow - wy * 14;
            const bool valid = jv && ((unsigned)(by8 + wy) < 128u)
                                  && ((unsigned)(bx8 + wx) < 128u);
            const int bb = (13 - wy) * 21 + (13 - wx);
            const int sw = ((kjc >> 1 ^ kjc >> 2) & 1) << 1;

            const float4 k0 = kw[hl][kjc][0 ^ sw];
            const float4 k1 = kw[hl][kjc][1 ^ sw];
            const float4 k2 = kw[hl][kjc][2 ^ sw];
            const float4 k3 = kw[hl][kjc][3 ^ sw];
            const float4 v0 = vw[hl][kjc][0 ^ sw];
            const float4 v1 = vw[hl][kjc][1 ^ sw];
            const float4 v2 = vw[hl][kjc][2 ^ sw];
            const float4 v3 = vw[hl][kjc][3 ^ sw];

#pragma unroll
            for (int qq = 0; qq < 4; ++qq) {
                const float* q = qreg[qq];
                float d = q[0] * k0.x;
                d = fmaf(q[1],  k0.y, d); d = fmaf(q[2],  k0.z, d); d = fmaf(q[3],  k0.w, d);
                d = fmaf(q[4],  k1.x, d); d = fmaf(q[5],  k1.y, d); d = fmaf(q[6],  k1.z, d);
                d = fmaf(q[7],  k1.w, d); d = fmaf(q[8],  k2.x, d); d = fmaf(q[9],  k2.y, d);
                d = fmaf(q[10], k2.z, d); d = fmaf(q[11], k2.w, d); d = fmaf(q[12], k3.x, d);
                d = fmaf(q[13], k3.y, d); d = fmaf(q[14], k3.z, d); d = fmaf(q[15], k3.w, d);
                const float lg = fmaf(d, 0.25f, bias_l[hl][bb + qoff[qq]]);
                const float p  = valid ? __expf(lg) : 0.f;
                sum[qq] += p;
                acc[qq][0]  = fmaf(p, v0.x, acc[qq][0]);
                acc[qq][1]  = fmaf(p, v0.y, acc[qq][1]);
                acc[qq][2]  = fmaf(p, v0.z, acc[qq][2]);
                acc[qq][3]  = fmaf(p, v0.w, acc[qq][3]);
                acc[qq][4]  = fmaf(p, v1.x, acc[qq][4]);
                acc[qq][5]  = fmaf(p, v1.y, acc[qq][5]);
                acc[qq][6]  = fmaf(p, v1.z, acc[qq][6]);
                acc[qq][7]  = fmaf(p, v1.w, acc[qq][7]);
                acc[qq][8]  = fmaf(p, v2.x, acc[qq][8]);
                acc[qq][9]  = fmaf(p, v2.y, acc[qq][9]);
                acc[qq][10] = fmaf(p, v2.z, acc[qq][10]);
                acc[qq][11] = fmaf(p, v2.w, acc[qq][11]);
                acc[qq][12] = fmaf(p, v3.x, acc[qq][12]);
                acc[qq][13] = fmaf(p, v3.y, acc[qq][13]);
                acc[qq][14] = fmaf(p, v3.z, acc[qq][14]);
                acc[qq][15] = fmaf(p, v3.w, acc[qq][15]);
            }
        }
        __syncthreads();   // all LDS reads done before next chunk's staging
    }

    // ---- reduce over the 4 quarter lanes (reduce-scatter, static indexing)
    const bool b1 = (quarter & 2) != 0;
    const bool b0 = (quarter & 1) != 0;
#pragma unroll
    for (int qq = 0; qq < 4; ++qq) {
        float s = sum[qq];
        s += __shfl_xor(s, 1);
        s += __shfl_xor(s, 2);
        const float inv = 1.0f / s;

        // xor-2 stage: keep my bit1-half, receive partner's copy of it
        float h[8];
#pragma unroll
        for (int k = 0; k < 8; ++k) {
            const float mine  = b1 ? acc[qq][8 + k] : acc[qq][k];
            const float theirs = b1 ? acc[qq][k] : acc[qq][8 + k];
            h[k] = mine + __shfl_xor(theirs, 2);
        }
        // xor-1 stage: keep my bit0-quarter
        float o[4];
#pragma unroll
        for (int k = 0; k < 4; ++k) {
            const float mine  = b0 ? h[4 + k] : h[k];
            const float theirs = b0 ? h[k] : h[4 + k];
            o[k] = (mine + __shfl_xor(theirs, 1)) * inv;
        }
        *(float4*)(qbase[qq] + quarter * 4) = make_float4(o[0], o[1], o[2], o[3]);
    }
}

// ---------------------------------------------------------------------------
extern "C" void kernel_launch(void* const* d_in, const int* in_sizes, int n_in,
                              void* d_out, int out_size, void* d_ws, size_t ws_size,
                              hipStream_t stream) {
    const float* x      = (const float*)d_in[0];
    const float* q_w    = (const float*)d_in[1];
    const float* kv_w   = (const float*)d_in[2];
    const float* pt     = (const float*)d_in[3];
    const float* proj_w = (const float*)d_in[4];
    const float* proj_b = (const float*)d_in[5];
    float* out = (float*)d_out;
    float* ykv = (float*)d_ws;   // (65536, 256)

    const dim3 blk(256);
    gemm_xbt<<<dim3(512, 3), blk, 0, stream>>>(x, 128, q_w, kv_w, nullptr,
                                               out, 128, ykv, 256);
    halo_attn<<<dim3(256, 4, 2), blk, 0, stream>>>(out, ykv, pt);
    gemm_xbt<<<dim3(512, 1), blk, 0, stream>>>(out, 128, proj_w, nullptr, proj_b,
                                               out, 128, nullptr, 128);
}

// Round 4
// 195.783 us; speedup vs baseline: 1.4989x; 1.2931x over previous
//
#include <hip/hip_runtime.h>
#include <float.h>

// HaloAttn: x(4,128,128,128) f32 -> out(4,128,128,128) f32
// BS=8, HS=3, WIN=14, NH=8, DQK=DV=16, SCALE=0.25
//
// k1: gemm_xbt  y_q = x @ q_w^T -> d_out, y_kv = x @ kv_w^T -> d_ws   (fp32)
// k2: halo_attn MFMA bf16: S^T = K·Q^T (swapped, K=32 builtin, d zero-padded)
//     -> exp2 -> PV (16x16x16, P C-frag == B-frag, zero shuffles)
// k3: gemm_xbt  d_out = d_out @ proj_w^T + proj_b (in place, fp32)

typedef float f32x4 __attribute__((ext_vector_type(4)));
typedef short s16x4 __attribute__((ext_vector_type(4)));
typedef short s16x8 __attribute__((ext_vector_type(8)));

__device__ inline ushort f2bf(float f) {   // RNE float->bf16
    unsigned u = __float_as_uint(f);
    return (ushort)((u + 0x7FFF + ((u >> 16) & 1)) >> 16);
}

// PV mfma: D = A(16x16 bf16)*B(16x16 bf16)+D. Builtin if present (compiler
// handles MFMA wait-state hazards); else inline asm + manual fences.
#if __has_builtin(__builtin_amdgcn_mfma_f32_16x16x16bf16_1k)
#define MFMA16(d, a, b) \
    d = __builtin_amdgcn_mfma_f32_16x16x16bf16_1k(a, b, d, 0, 0, 0)
#define MFMA_FENCE() ((void)0)
#else
#define MFMA16(d, a, b) \
    asm volatile("v_mfma_f32_16x16x16_bf16 %0, %1, %2, %0" \
                 : "+v"(d) : "v"(a), "v"(b))
// HW wait-states: VALU->MFMA srcA/B (2) and MFMA->VALU read (~5 for 4-pass).
// sched_barrier(0) pins order (rule #18); s_nops provide the cycles.
#define MFMA_FENCE() do {                                   \
    __builtin_amdgcn_sched_barrier(0);                      \
    asm volatile("s_nop 7\n\ts_nop 7" ::: "memory");        \
    __builtin_amdgcn_sched_barrier(0);                      \
} while (0)
#endif

// ---------------------------------------------------------------------------
__global__ __launch_bounds__(256) void gemm_xbt(
    const float* A, int lda,
    const float* __restrict__ Bq, const float* __restrict__ Bkv,
    const float* __restrict__ bias,
    float* Cq, int ldcq, float* Ckv, int ldckv)
{
    __shared__ float aT[32][132];
    __shared__ float bT[32][132];

    const int t  = threadIdx.x;
    const int mt = blockIdx.x, nt = blockIdx.y;

    const float* Bt = (nt == 0) ? Bq : (Bkv + (size_t)(nt - 1) * (128 * 128));
    float*       C  = (nt == 0) ? Cq : Ckv;
    const int    ldc  = (nt == 0) ? ldcq : ldckv;
    const int    col0 = (nt == 0) ? 0 : (nt - 1) * 128;
    const int    row0 = mt * 128;

    const int tr = t >> 4, tc = t & 15;

    float acc[8][8];
#pragma unroll
    for (int i = 0; i < 8; ++i)
#pragma unroll
        for (int j = 0; j < 8; ++j) acc[i][j] = 0.f;

#pragma unroll 1
    for (int k0 = 0; k0 < 128; k0 += 32) {
#pragma unroll
        for (int i = t; i < 1024; i += 256) {
            int r = i >> 3, k4 = i & 7;
            const float4 v = *(const float4*)(A + (size_t)(row0 + r) * lda + k0 + k4 * 4);
            aT[k4*4+0][r] = v.x; aT[k4*4+1][r] = v.y;
            aT[k4*4+2][r] = v.z; aT[k4*4+3][r] = v.w;
        }
#pragma unroll
        for (int i = t; i < 1024; i += 256) {
            int r = i >> 3, k4 = i & 7;
            const float4 v = *(const float4*)(Bt + (size_t)r * 128 + k0 + k4 * 4);
            bT[k4*4+0][r] = v.x; bT[k4*4+1][r] = v.y;
            bT[k4*4+2][r] = v.z; bT[k4*4+3][r] = v.w;
        }
        __syncthreads();
#pragma unroll
        for (int k = 0; k < 32; ++k) {
            const float4 a0 = *(const float4*)&aT[k][tr * 4];
            const float4 a1 = *(const float4*)&aT[k][64 + tr * 4];
            const float4 b0 = *(const float4*)&bT[k][tc * 4];
            const float4 b1 = *(const float4*)&bT[k][64 + tc * 4];
            const float av[8] = {a0.x,a0.y,a0.z,a0.w,a1.x,a1.y,a1.z,a1.w};
            const float bv[8] = {b0.x,b0.y,b0.z,b0.w,b1.x,b1.y,b1.z,b1.w};
#pragma unroll
            for (int i = 0; i < 8; ++i)
#pragma unroll
                for (int j = 0; j < 8; ++j)
                    acc[i][j] = fmaf(av[i], bv[j], acc[i][j]);
        }
        __syncthreads();
    }

#pragma unroll
    for (int ih = 0; ih < 2; ++ih)
#pragma unroll
    for (int ii = 0; ii < 4; ++ii) {
        const int r = row0 + ih * 64 + tr * 4 + ii;
#pragma unroll
        for (int jh = 0; jh < 2; ++jh) {
            const int c = col0 + jh * 64 + tc * 4;
            float4 v;
            v.x = acc[ih*4+ii][jh*4+0]; v.y = acc[ih*4+ii][jh*4+1];
            v.z = acc[ih*4+ii][jh*4+2]; v.w = acc[ih*4+ii][jh*4+3];
            if (bias) {
                const int cb = (jh * 64 + tc * 4);
                v.x += bias[cb]; v.y += bias[cb+1]; v.z += bias[cb+2]; v.w += bias[cb+3];
            }
            *(float4*)(C + (size_t)r * ldc + c) = v;
        }
    }
}

// ---------------------------------------------------------------------------
// MFMA halo attention. grid(256 spatial blocks, 4 batch), 256 threads = 4 waves.
// 2 rounds x 4 heads; wave hl handles head round*4+hl.
// QK (swapped): S^T = K·Q^T via mfma_f32_16x16x32_bf16, contraction d=16
// zero-padded to 32 (lane groups cA>=2 carry zero frags). C-frag: col=q=l&15,
// row=key=(l>>4)*4+reg -> exactly the B-frag of the 16x16x16 PV mfma.
__global__ __launch_bounds__(256) void halo_attn(
    float* qout,                          // q in, attn-out out (65536 x 128)
    const float* __restrict__ kv,         // (65536 x 256): head h -> k h*32, v h*32+16
    const float* __restrict__ pos_table)  // (729, 8)
{
    __shared__ ushort VT[4][16][208];     // [head][dim][key] bf16   26624 B
    __shared__ float  bias_l[4][441];     // bias * log2e             7056 B
    __shared__ int    keyoff[208];        // byte offset into kv (0 if invalid)
    __shared__ float  kmask[208];         // 0 valid / -1000 masked
    __shared__ short  koff2[208];         // ky*21+kx

    const int t  = threadIdx.x;
    const int bi = blockIdx.x, b = blockIdx.y;
    const int by = bi >> 4, bx = bi & 15;
    const int hl = t >> 6;                 // wave id
    const int l  = t & 63;
    const int lr = l & 15;                 // frag row/col lane
    const int cA = l >> 4;                 // frag k-chunk

    const char* kvb = (const char*)kv + (size_t)b * (128 * 128 * 256 * 4);

    // ---- per-block LUTs
    if (t < 208) {
        const int wy = t / 14, wx = t - (t / 14) * 14;
        const int py = by * 8 + wy - 3, px = bx * 8 + wx - 3;
        const bool valid = (t < 196) && ((unsigned)py < 128u) && ((unsigned)px < 128u);
        keyoff[t] = valid ? ((py * 128 + px) * 1024) : 0;
        kmask[t]  = valid ? 0.f : -1000.f;
        koff2[t]  = (t < 196) ? (short)(wy * 21 + wx) : (short)0;
    }
    __syncthreads();

#pragma unroll 1
    for (int round = 0; round < 2; ++round) {
        // ---- stage bias (4 heads, pre-scaled by log2e)
        for (int i = t; i < 1764; i += 256) {
            const int hh = i / 441, r = i - hh * 441;
            const int ry = r / 21, rx = r - ry * 21;
            bias_l[hh][r] = pos_table[((ry + 3) * 27 + rx + 3) * 8 + round * 4 + hh]
                          * 1.44269504f;
        }
        // ---- stage V^T (4 heads; 2 keys per item -> u32 writes)
        for (int i = t; i < 512; i += 256) {
            const int h = i >> 7, kp = i & 127;
            if (kp < 104) {
                const char* base = kvb + (round * 4 + h) * 128 + 64;
                const float4* s0 = (const float4*)(base + keyoff[2 * kp]);
                const float4* s1 = (const float4*)(base + keyoff[2 * kp + 1]);
#pragma unroll
                for (int j = 0; j < 4; ++j) {
                    const float4 a = s0[j];
                    const float4 c = s1[j];
                    *(unsigned*)&VT[h][j*4+0][2*kp] = ((unsigned)f2bf(c.x) << 16) | f2bf(a.x);
                    *(unsigned*)&VT[h][j*4+1][2*kp] = ((unsigned)f2bf(c.y) << 16) | f2bf(a.y);
                    *(unsigned*)&VT[h][j*4+2][2*kp] = ((unsigned)f2bf(c.z) << 16) | f2bf(a.z);
                    *(unsigned*)&VT[h][j*4+3][2*kp] = ((unsigned)f2bf(c.w) << 16) | f2bf(a.w);
                }
            }
        }
        __syncthreads();

        // ---- compute: wave hl -> head
        const int head = round * 4 + hl;

        // Q^T B-frags (K=32 layout: lane holds d = cA*8..cA*8+7; zero for cA>=2)
        s16x8 qf[4];
        float* qptr[4];
        int qoff2[4];
#pragma unroll
        for (int qt = 0; qt < 4; ++qt) {
            const int q = qt * 16 + lr;
            const int qy = q >> 3, qx = q & 7;
            qoff2[qt] = (qy + 13) * 21 + (qx + 13);
            float* p = qout + (((size_t)(b * 128 + by * 8 + qy)) * 128 + bx * 8 + qx) * 128
                     + head * 16;
            qptr[qt] = p + cA * 4;               // store ptr (D-frag dims cA*4..+3)
#pragma unroll
            for (int j = 0; j < 8; ++j) qf[qt][j] = 0;
            if (cA < 2) {
                const float4 q0 = *(const float4*)(p + cA * 8);
                const float4 q1 = *(const float4*)(p + cA * 8 + 4);
                qf[qt][0] = (short)f2bf(q0.x); qf[qt][1] = (short)f2bf(q0.y);
                qf[qt][2] = (short)f2bf(q0.z); qf[qt][3] = (short)f2bf(q0.w);
                qf[qt][4] = (short)f2bf(q1.x); qf[qt][5] = (short)f2bf(q1.y);
                qf[qt][6] = (short)f2bf(q1.z); qf[qt][7] = (short)f2bf(q1.w);
            }
        }

        f32x4 accv[4];
        float sumf[4];
#pragma unroll
        for (int qt = 0; qt < 4; ++qt) {
            accv[qt] = (f32x4){0.f, 0.f, 0.f, 0.f};
            sumf[qt] = 0.f;
        }

#pragma unroll 1
        for (int kt = 0; kt < 13; ++kt) {
            // QK A-frag: K[key=kt*16+lr][d=cA*8..+7] (zero for cA>=2)
            s16x8 ak;
#pragma unroll
            for (int j = 0; j < 8; ++j) ak[j] = 0;
            if (cA < 2) {
                const char* kp = kvb + keyoff[kt * 16 + lr] + head * 128 + cA * 32;
                const float4 k0 = *(const float4*)kp;
                const float4 k1 = *(const float4*)(kp + 16);
                ak[0] = (short)f2bf(k0.x); ak[1] = (short)f2bf(k0.y);
                ak[2] = (short)f2bf(k0.z); ak[3] = (short)f2bf(k0.w);
                ak[4] = (short)f2bf(k1.x); ak[5] = (short)f2bf(k1.y);
                ak[6] = (short)f2bf(k1.z); ak[7] = (short)f2bf(k1.w);
            }

            f32x4 sf[4];
#pragma unroll
            for (int qt = 0; qt < 4; ++qt)
                sf[qt] = __builtin_amdgcn_mfma_f32_16x16x32_bf16(
                             ak, qf[qt], (f32x4){0.f, 0.f, 0.f, 0.f}, 0, 0, 0);

            const int kb = kt * 16 + cA * 4;           // this lane's 4 keys
            const s16x4 kk = *(const s16x4*)&koff2[kb];
            const f32x4 km = *(const f32x4*)&kmask[kb];
            const s16x4 vt = *(const s16x4*)&VT[hl][lr][kb];  // PV A-frag (dim=lr)

#pragma unroll
            for (int qt = 0; qt < 4; ++qt) {
                float pr[4];
#pragma unroll
                for (int r = 0; r < 4; ++r) {
                    const int idx = qoff2[qt] - (int)kk[r];
                    const float arg = fmaf(sf[qt][r], 0.36067376f,
                                           bias_l[hl][idx] + km[r]);
                    pr[r] = exp2f(arg);
                    sumf[qt] += pr[r];
                }
                s16x4 pb;
                pb[0] = (short)f2bf(pr[0]); pb[1] = (short)f2bf(pr[1]);
                pb[2] = (short)f2bf(pr[2]); pb[3] = (short)f2bf(pr[3]);
                MFMA_FENCE();                  // VALU pack -> MFMA srcB hazard
                MFMA16(accv[qt], vt, pb);
            }
        }
        MFMA_FENCE();                          // MFMA -> VALU read hazard

        // ---- normalize + store (O^T frag: col=q=lr, row=dim=cA*4+r)
#pragma unroll
        for (int qt = 0; qt < 4; ++qt) {
            float s = sumf[qt];
            s += __shfl_xor(s, 16);
            s += __shfl_xor(s, 32);
            const float inv = 1.0f / s;
            f32x4 o = accv[qt] * inv;
            *(f32x4*)qptr[qt] = o;
        }
        __syncthreads();   // protect VT/bias before next round's staging
    }
}

// ---------------------------------------------------------------------------
extern "C" void kernel_launch(void* const* d_in, const int* in_sizes, int n_in,
                              void* d_out, int out_size, void* d_ws, size_t ws_size,
                              hipStream_t stream) {
    const float* x      = (const float*)d_in[0];
    const float* q_w    = (const float*)d_in[1];
    const float* kv_w   = (const float*)d_in[2];
    const float* pt     = (const float*)d_in[3];
    const float* proj_w = (const float*)d_in[4];
    const float* proj_b = (const float*)d_in[5];
    float* out = (float*)d_out;
    float* ykv = (float*)d_ws;   // (65536, 256)

    const dim3 blk(256);
    gemm_xbt<<<dim3(512, 3), blk, 0, stream>>>(x, 128, q_w, kv_w, nullptr,
                                               out, 128, ykv, 256);
    halo_attn<<<dim3(256, 4), blk, 0, stream>>>(out, ykv, pt);
    gemm_xbt<<<dim3(512, 1), blk, 0, stream>>>(out, 128, proj_w, nullptr, proj_b,
                                               out, 128, nullptr, 128);
}

// Round 5
// 137.824 us; speedup vs baseline: 2.1293x; 1.4205x over previous
//
#include <hip/hip_runtime.h>
#include <float.h>

// HaloAttn: x(4,128,128,128) f32 -> out(4,128,128,128) f32
// BS=8, HS=3, WIN=14, NH=8, DQK=DV=16, SCALE=0.25
//
// k0: conv_w      q_w|kv_w|proj_w (512x128 f32) -> hi/lo bf16 in ws
// k1: gemm_split  q=x@q_w^T -> ws bf16, kv=x@kv_w^T -> ws bf16   (3-term split MFMA)
// k2: halo_attn   MFMA bf16 (swapped QK, P C-frag == PV B-frag) -> d_out fp32
// k3: gemm_split  d_out = d_out @ proj_w^T + proj_b (in place, split MFMA)
//
// ws layout: ykv bf16 [65536][256] @0 (32MB) | q bf16 [65536][128] @32M (16MB)
//            | whi[512][128] @48M (128KB) | wlo (128KB).  Total ~48.5MB.

typedef float f32x4 __attribute__((ext_vector_type(4)));
typedef short s16x4 __attribute__((ext_vector_type(4)));
typedef short s16x8 __attribute__((ext_vector_type(8)));
typedef unsigned int u32x2 __attribute__((ext_vector_type(2)));

__device__ inline ushort f2bf(float f) {   // RNE float->bf16
    unsigned u = __float_as_uint(f);
    return (ushort)((u + 0x7FFF + ((u >> 16) & 1)) >> 16);
}
__device__ inline float bf2f(ushort h) { return __uint_as_float((unsigned)h << 16); }
__device__ inline unsigned pack2(float a, float b) {
    return (unsigned)f2bf(a) | ((unsigned)f2bf(b) << 16);
}

// PV mfma (16x16x16): builtin if present, else fenced inline asm (R4-verified).
#if __has_builtin(__builtin_amdgcn_mfma_f32_16x16x16bf16_1k)
#define MFMA16(d, a, b) \
    d = __builtin_amdgcn_mfma_f32_16x16x16bf16_1k(a, b, d, 0, 0, 0)
#define MFMA_FENCE() ((void)0)
#else
#define MFMA16(d, a, b) \
    asm volatile("v_mfma_f32_16x16x16_bf16 %0, %1, %2, %0" \
                 : "+v"(d) : "v"(a), "v"(b))
#define MFMA_FENCE() do {                                   \
    __builtin_amdgcn_sched_barrier(0);                      \
    asm volatile("s_nop 7\n\ts_nop 7" ::: "memory");        \
    __builtin_amdgcn_sched_barrier(0);                      \
} while (0)
#endif

// ---------------------------------------------------------------------------
// Weight split: rows 0-127 q_w, 128-383 kv_w, 384-511 proj_w. 65536 elems.
__global__ __launch_bounds__(256) void conv_w(
    const float* __restrict__ q_w, const float* __restrict__ kv_w,
    const float* __restrict__ proj_w, ushort* whi, ushort* wlo)
{
    const int g = blockIdx.x * 256 + threadIdx.x;      // 0..65535
    const int row = g >> 7, col = g & 127;
    const float v = (row < 128) ? q_w[row * 128 + col]
                  : (row < 384) ? kv_w[(row - 128) * 128 + col]
                                : proj_w[(row - 384) * 128 + col];
    const ushort h = f2bf(v);
    whi[g] = h;
    wlo[g] = f2bf(v - bf2f(h));
}

// ---------------------------------------------------------------------------
// Split-bf16 MFMA GEMM: C[row0..+127][chan] = A(fp32) @ W^T (+bias).
// Swapped operands: mfma(A=w_frag, B=x_frag) -> lane(l&15)=pixel holds 4
// consecutive chans (cA*4+r). A-tile (full K=128) split hi/lo into swizzled
// LDS once per block; W-frags from global (L1/L2-hot). 4 waves = 2x2 of 64x64.
__global__ __launch_bounds__(256, 2) void gemm_split(
    const float* A,                                   // [M][128] fp32
    const ushort* __restrict__ Whi, const ushort* __restrict__ Wlo,
    int wbase, int ntc, int tok1,
    ushort* qb, ushort* kvb, float* outf, const float* __restrict__ bias)
{
    __shared__ ushort Ah[128 * 128];   // [row][k] swizzled 16B chunks, 32KB
    __shared__ ushort Al[128 * 128];

    const int t = threadIdx.x;
    const int row0 = blockIdx.x * 128;
    const int w = t >> 6, l = t & 63;
    const int wm = w >> 1, wn = w & 1;
    const int lr = l & 15, cA = l >> 4;

    // ---- stage + split A (coalesced float4; chunk-XOR swizzle: chunk^=(row&7))
#pragma unroll
    for (int i = 0; i < 16; ++i) {
        const int idx = t + i * 256;
        const int p = idx >> 5, fc = idx & 31;         // row, float4-col
        const float4 v = *(const float4*)(A + (size_t)(row0 + p) * 128 + fc * 4);
        const int base = p * 128 + (((fc >> 1) ^ (p & 7)) << 3) + (fc & 1) * 4;
        const ushort h0 = f2bf(v.x), h1 = f2bf(v.y), h2 = f2bf(v.z), h3 = f2bf(v.w);
        *(u32x2*)&Ah[base] = (u32x2){ (unsigned)h0 | ((unsigned)h1 << 16),
                                      (unsigned)h2 | ((unsigned)h3 << 16) };
        *(u32x2*)&Al[base] = (u32x2){
            pack2(v.x - bf2f(h0), v.y - bf2f(h1)),
            pack2(v.z - bf2f(h2), v.w - bf2f(h3)) };
    }
    __syncthreads();

#pragma unroll 1
    for (int nt = 0; nt < ntc; ++nt) {
        f32x4 acc[4][4];                               // [mf][nf]
#pragma unroll
        for (int mf = 0; mf < 4; ++mf)
#pragma unroll
            for (int nf = 0; nf < 4; ++nf) acc[mf][nf] = (f32x4){0.f,0.f,0.f,0.f};

#pragma unroll
        for (int kk = 0; kk < 4; ++kk) {
            s16x8 xh[4], xl[4], wh[4], wl[4];
#pragma unroll
            for (int mf = 0; mf < 4; ++mf) {
                const int p = wm * 64 + mf * 16 + lr;
                const int off = p * 128 + ((((kk << 2) + cA) ^ (p & 7)) << 3);
                xh[mf] = *(const s16x8*)&Ah[off];
                xl[mf] = *(const s16x8*)&Al[off];
            }
#pragma unroll
            for (int nf = 0; nf < 4; ++nf) {
                const size_t off = (size_t)(wbase + nt * 128 + wn * 64 + nf * 16 + lr) * 128
                                 + kk * 32 + cA * 8;
                wh[nf] = *(const s16x8*)&Whi[off];
                wl[nf] = *(const s16x8*)&Wlo[off];
            }
#pragma unroll
            for (int nf = 0; nf < 4; ++nf)
#pragma unroll
                for (int mf = 0; mf < 4; ++mf) {
                    acc[mf][nf] = __builtin_amdgcn_mfma_f32_16x16x32_bf16(
                                      wh[nf], xh[mf], acc[mf][nf], 0, 0, 0);
                    acc[mf][nf] = __builtin_amdgcn_mfma_f32_16x16x32_bf16(
                                      wh[nf], xl[mf], acc[mf][nf], 0, 0, 0);
                    acc[mf][nf] = __builtin_amdgcn_mfma_f32_16x16x32_bf16(
                                      wl[nf], xh[mf], acc[mf][nf], 0, 0, 0);
                }
        }

        // ---- store: pixel = row0+wm*64+mf*16+lr, chan = wn*64+nf*16+cA*4+r
#pragma unroll
        for (int mf = 0; mf < 4; ++mf) {
            const size_t pix = row0 + wm * 64 + mf * 16 + lr;
#pragma unroll
            for (int nf = 0; nf < 4; ++nf) {
                const int chan = wn * 64 + nf * 16 + cA * 4;
                const f32x4 o = acc[mf][nf];
                if (tok1) {
                    const u32x2 pk = (u32x2){ pack2(o[0], o[1]), pack2(o[2], o[3]) };
                    if (nt == 0) *(u32x2*)(qb + pix * 128 + chan) = pk;
                    else         *(u32x2*)(kvb + pix * 256 + (nt - 1) * 128 + chan) = pk;
                } else {
                    const float4 bv = *(const float4*)(bias + chan);
                    f32x4 r = o;
                    r[0] += bv.x; r[1] += bv.y; r[2] += bv.z; r[3] += bv.w;
                    *(f32x4*)(outf + pix * 128 + chan) = r;
                }
            }
        }
    }
}

// ---------------------------------------------------------------------------
// MFMA halo attention (R4 structure, bf16 q/kv sources, fp32 out to d_out).
// grid(256 spatial blocks, 4 batch), 256 threads = 4 waves; 2 rounds x 4 heads.
// QK (swapped): S^T = K·Q^T via mfma_f32_16x16x32_bf16 (d=16 zero-padded).
// C-frag (col=q=l&15, row=key=(l>>4)*4+r) == B-frag of the 16x16x16 PV mfma.
__global__ __launch_bounds__(256) void halo_attn(
    float* out,                           // d_out fp32 (65536 x 128)
    const ushort* __restrict__ qg,        // ws q bf16 (65536 x 128)
    const ushort* __restrict__ kvg,       // ws kv bf16 (65536 x 256): h -> k h*32, v h*32+16
    const float* __restrict__ pos_table)  // (729, 8)
{
    __shared__ ushort VT[4][16][208];     // [head][dim][key] bf16   26624 B
    __shared__ float  bias_l[4][441];     // bias * log2e             7056 B
    __shared__ int    keyoff[208];        // byte offset into kv (0 if invalid)
    __shared__ float  kmask[208];         // 0 valid / -1000 masked
    __shared__ short  koff2[208];         // ky*21+kx

    const int t  = threadIdx.x;
    const int bi = blockIdx.x, b = blockIdx.y;
    const int by = bi >> 4, bx = bi & 15;
    const int hl = t >> 6;                 // wave id
    const int l  = t & 63;
    const int lr = l & 15;
    const int cA = l >> 4;

    const char* kvb = (const char*)kvg + (size_t)b * (128 * 128 * 256 * 2);

    if (t < 208) {
        const int wy = t / 14, wx = t - (t / 14) * 14;
        const int py = by * 8 + wy - 3, px = bx * 8 + wx - 3;
        const bool valid = (t < 196) && ((unsigned)py < 128u) && ((unsigned)px < 128u);
        keyoff[t] = valid ? ((py * 128 + px) * 512) : 0;
        kmask[t]  = valid ? 0.f : -1000.f;
        koff2[t]  = (t < 196) ? (short)(wy * 21 + wx) : (short)0;
    }
    __syncthreads();

#pragma unroll 1
    for (int round = 0; round < 2; ++round) {
        for (int i = t; i < 1764; i += 256) {
            const int hh = i / 441, r = i - hh * 441;
            const int ry = r / 21, rx = r - ry * 21;
            bias_l[hh][r] = pos_table[((ry + 3) * 27 + rx + 3) * 8 + round * 4 + hh]
                          * 1.44269504f;
        }
        // ---- stage V^T (bf16 source; 2 keys per item -> u32 writes)
        for (int i = t; i < 512; i += 256) {
            const int h = i >> 7, kp = i & 127;
            if (kp < 104) {
                const char* base = kvb + (round * 4 + h) * 64 + 32;
                const char* s0 = base + keyoff[2 * kp];
                const char* s1 = base + keyoff[2 * kp + 1];
                const s16x8 a0 = *(const s16x8*)s0;
                const s16x8 a1 = *(const s16x8*)(s0 + 16);
                const s16x8 c0 = *(const s16x8*)s1;
                const s16x8 c1 = *(const s16x8*)(s1 + 16);
#pragma unroll
                for (int j = 0; j < 8; ++j) {
                    *(unsigned*)&VT[h][j][2 * kp] =
                        ((unsigned)(ushort)c0[j] << 16) | (ushort)a0[j];
                    *(unsigned*)&VT[h][j + 8][2 * kp] =
                        ((unsigned)(ushort)c1[j] << 16) | (ushort)a1[j];
                }
            }
        }
        __syncthreads();

        const int head = round * 4 + hl;

        // Q^T B-frags (K=32: lane holds d=cA*8..+7; zero for cA>=2)
        s16x8 qf[4];
        float* qptr[4];
        int qoff2[4];
#pragma unroll
        for (int qt = 0; qt < 4; ++qt) {
            const int q = qt * 16 + lr;
            const int qy = q >> 3, qx = q & 7;
            qoff2[qt] = (qy + 13) * 21 + (qx + 13);
            const size_t pix = ((size_t)(b * 128 + by * 8 + qy)) * 128 + bx * 8 + qx;
            qptr[qt] = out + pix * 128 + head * 16 + cA * 4;
#pragma unroll
            for (int j = 0; j < 8; ++j) qf[qt][j] = 0;
            if (cA < 2)
                qf[qt] = *(const s16x8*)(qg + pix * 128 + head * 16 + cA * 8);
        }

        f32x4 accv[4];
        float sumf[4];
#pragma unroll
        for (int qt = 0; qt < 4; ++qt) {
            accv[qt] = (f32x4){0.f, 0.f, 0.f, 0.f};
            sumf[qt] = 0.f;
        }

#pragma unroll 1
        for (int kt = 0; kt < 13; ++kt) {
            s16x8 ak;
#pragma unroll
            for (int j = 0; j < 8; ++j) ak[j] = 0;
            if (cA < 2)
                ak = *(const s16x8*)(kvb + keyoff[kt * 16 + lr] + head * 64 + cA * 16);

            f32x4 sf[4];
#pragma unroll
            for (int qt = 0; qt < 4; ++qt)
                sf[qt] = __builtin_amdgcn_mfma_f32_16x16x32_bf16(
                             ak, qf[qt], (f32x4){0.f, 0.f, 0.f, 0.f}, 0, 0, 0);

            const int kb = kt * 16 + cA * 4;
            const s16x4 kk = *(const s16x4*)&koff2[kb];
            const f32x4 km = *(const f32x4*)&kmask[kb];
            const s16x4 vt = *(const s16x4*)&VT[hl][lr][kb];

#pragma unroll
            for (int qt = 0; qt < 4; ++qt) {
                float pr[4];
#pragma unroll
                for (int r = 0; r < 4; ++r) {
                    const int idx = qoff2[qt] - (int)kk[r];
                    const float arg = fmaf(sf[qt][r], 0.36067376f,
                                           bias_l[hl][idx] + km[r]);
                    pr[r] = exp2f(arg);
                    sumf[qt] += pr[r];
                }
                s16x4 pb;
                pb[0] = (short)f2bf(pr[0]); pb[1] = (short)f2bf(pr[1]);
                pb[2] = (short)f2bf(pr[2]); pb[3] = (short)f2bf(pr[3]);
                MFMA_FENCE();
                MFMA16(accv[qt], vt, pb);
            }
        }
        MFMA_FENCE();

#pragma unroll
        for (int qt = 0; qt < 4; ++qt) {
            float s = sumf[qt];
            s += __shfl_xor(s, 16);
            s += __shfl_xor(s, 32);
            const float inv = 1.0f / s;
            f32x4 o = accv[qt] * inv;
            *(f32x4*)qptr[qt] = o;
        }
        __syncthreads();
    }
}

// ---------------------------------------------------------------------------
extern "C" void kernel_launch(void* const* d_in, const int* in_sizes, int n_in,
                              void* d_out, int out_size, void* d_ws, size_t ws_size,
                              hipStream_t stream) {
    const float* x      = (const float*)d_in[0];
    const float* q_w    = (const float*)d_in[1];
    const float* kv_w   = (const float*)d_in[2];
    const float* pt     = (const float*)d_in[3];
    const float* proj_w = (const float*)d_in[4];
    const float* proj_b = (const float*)d_in[5];
    float* out = (float*)d_out;

    ushort* ykvb = (ushort*)d_ws;                                   // 32 MB
    ushort* qb   = (ushort*)((char*)d_ws + 33554432);               // 16 MB
    ushort* whi  = (ushort*)((char*)d_ws + 33554432 + 16777216);    // 128 KB
    ushort* wlo  = whi + 65536;                                     // 128 KB

    const dim3 blk(256);
    conv_w<<<dim3(256), blk, 0, stream>>>(q_w, kv_w, proj_w, whi, wlo);
    gemm_split<<<dim3(512), blk, 0, stream>>>(x, whi, wlo, 0, 3, 1,
                                              qb, ykvb, nullptr, nullptr);
    halo_attn<<<dim3(256, 4), blk, 0, stream>>>(out, qb, ykvb, pt);
    gemm_split<<<dim3(512), blk, 0, stream>>>(out, whi, wlo, 384, 1, 0,
                                              nullptr, nullptr, out, proj_b);
}

// Round 7
// 134.759 us; speedup vs baseline: 2.1777x; 1.0228x over previous
//
#include <hip/hip_runtime.h>
#include <float.h>

// HaloAttn: x(4,128,128,128) f32 -> out(4,128,128,128) f32
// BS=8, HS=3, WIN=14, NH=8, DQK=DV=16, SCALE=0.25
//
// k0: conv_w      q_w|kv_w|proj_w (512x128 f32) -> hi/lo bf16 in ws
// k1: gemm_split  q=x@q_w^T -> ws bf16, kv=x@kv_w^T -> ws bf16   (3-term split MFMA)
// k2: halo_attn   1 head/block (grid.z=8), 1 q-tile/wave; MFMA bf16 swapped QK
// k3: gemm_split  d_out = d_out @ proj_w^T + proj_b (in place, split MFMA)
//
// R7 = R6 structure with R5-proven inner ops (bisect): f2bf/pack2 packing,
// short-LUT array-indexed bias gather, no forced launch_bounds min-waves.
//
// ws layout: ykv bf16 [65536][256] @0 (32MB) | q bf16 [65536][128] @32M (16MB)
//            | whi[512][128] @48M (128KB) | wlo (128KB).

typedef float f32x4 __attribute__((ext_vector_type(4)));
typedef short s16x4 __attribute__((ext_vector_type(4)));
typedef short s16x8 __attribute__((ext_vector_type(8)));
typedef unsigned int u32x2 __attribute__((ext_vector_type(2)));

__device__ inline ushort f2bf(float f) {   // RNE float->bf16
    unsigned u = __float_as_uint(f);
    return (ushort)((u + 0x7FFF + ((u >> 16) & 1)) >> 16);
}
__device__ inline float bf2f(ushort h) { return __uint_as_float((unsigned)h << 16); }
__device__ inline unsigned pack2(float a, float b) {
    return (unsigned)f2bf(a) | ((unsigned)f2bf(b) << 16);
}

// PV mfma (16x16x16): builtin if present, else fenced inline asm (R4-verified).
#if __has_builtin(__builtin_amdgcn_mfma_f32_16x16x16bf16_1k)
#define MFMA16(d, a, b) \
    d = __builtin_amdgcn_mfma_f32_16x16x16bf16_1k(a, b, d, 0, 0, 0)
#define MFMA_FENCE() ((void)0)
#else
#define MFMA16(d, a, b) \
    asm volatile("v_mfma_f32_16x16x16_bf16 %0, %1, %2, %0" \
                 : "+v"(d) : "v"(a), "v"(b))
#define MFMA_FENCE() do {                                   \
    __builtin_amdgcn_sched_barrier(0);                      \
    asm volatile("s_nop 7\n\ts_nop 7" ::: "memory");        \
    __builtin_amdgcn_sched_barrier(0);                      \
} while (0)
#endif

// ---------------------------------------------------------------------------
// Weight split: rows 0-127 q_w, 128-383 kv_w, 384-511 proj_w. 65536 elems.
__global__ __launch_bounds__(256) void conv_w(
    const float* __restrict__ q_w, const float* __restrict__ kv_w,
    const float* __restrict__ proj_w, ushort* whi, ushort* wlo)
{
    const int g = blockIdx.x * 256 + threadIdx.x;      // 0..65535
    const int row = g >> 7, col = g & 127;
    const float v = (row < 128) ? q_w[row * 128 + col]
                  : (row < 384) ? kv_w[(row - 128) * 128 + col]
                                : proj_w[(row - 384) * 128 + col];
    const ushort h = f2bf(v);
    whi[g] = h;
    wlo[g] = f2bf(v - bf2f(h));
}

// ---------------------------------------------------------------------------
// Split-bf16 MFMA GEMM: C[row0..+127][chan] = A(fp32) @ W^T (+bias).
// Swapped operands: mfma(A=w_frag, B=x_frag) -> lane(l&15)=pixel holds 4
// consecutive chans. A-tile (full K=128) split hi/lo into swizzled LDS once
// per block; W-frags from global (L2-hot). 4 waves = 2x2 of 64x64.
__global__ __launch_bounds__(256, 2) void gemm_split(
    const float* A,                                   // [M][128] fp32
    const ushort* __restrict__ Whi, const ushort* __restrict__ Wlo,
    int wbase, int ntc, int tok1,
    ushort* qb, ushort* kvb, float* outf, const float* __restrict__ bias)
{
    __shared__ ushort Ah[128 * 128];   // [row][k] swizzled 16B chunks, 32KB
    __shared__ ushort Al[128 * 128];

    const int t = threadIdx.x;
    const int row0 = blockIdx.x * 128;
    const int w = t >> 6, l = t & 63;
    const int wm = w >> 1, wn = w & 1;
    const int lr = l & 15, cA = l >> 4;

    // ---- stage + split A (coalesced float4; chunk-XOR swizzle: chunk^=(row&7))
#pragma unroll
    for (int i = 0; i < 16; ++i) {
        const int idx = t + i * 256;
        const int p = idx >> 5, fc = idx & 31;         // row, float4-col
        const float4 v = *(const float4*)(A + (size_t)(row0 + p) * 128 + fc * 4);
        const int base = p * 128 + (((fc >> 1) ^ (p & 7)) << 3) + (fc & 1) * 4;
        const ushort h0 = f2bf(v.x), h1 = f2bf(v.y), h2 = f2bf(v.z), h3 = f2bf(v.w);
        *(u32x2*)&Ah[base] = (u32x2){ (unsigned)h0 | ((unsigned)h1 << 16),
                                      (unsigned)h2 | ((unsigned)h3 << 16) };
        *(u32x2*)&Al[base] = (u32x2){
            pack2(v.x - bf2f(h0), v.y - bf2f(h1)),
            pack2(v.z - bf2f(h2), v.w - bf2f(h3)) };
    }
    __syncthreads();

#pragma unroll 1
    for (int nt = 0; nt < ntc; ++nt) {
        f32x4 acc[4][4];                               // [mf][nf]
#pragma unroll
        for (int mf = 0; mf < 4; ++mf)
#pragma unroll
            for (int nf = 0; nf < 4; ++nf) acc[mf][nf] = (f32x4){0.f,0.f,0.f,0.f};

#pragma unroll
        for (int kk = 0; kk < 4; ++kk) {
            s16x8 xh[4], xl[4], wh[4], wl[4];
#pragma unroll
            for (int mf = 0; mf < 4; ++mf) {
                const int p = wm * 64 + mf * 16 + lr;
                const int off = p * 128 + ((((kk << 2) + cA) ^ (p & 7)) << 3);
                xh[mf] = *(const s16x8*)&Ah[off];
                xl[mf] = *(const s16x8*)&Al[off];
            }
#pragma unroll
            for (int nf = 0; nf < 4; ++nf) {
                const size_t off = (size_t)(wbase + nt * 128 + wn * 64 + nf * 16 + lr) * 128
                                 + kk * 32 + cA * 8;
                wh[nf] = *(const s16x8*)&Whi[off];
                wl[nf] = *(const s16x8*)&Wlo[off];
            }
#pragma unroll
            for (int nf = 0; nf < 4; ++nf)
#pragma unroll
                for (int mf = 0; mf < 4; ++mf) {
                    acc[mf][nf] = __builtin_amdgcn_mfma_f32_16x16x32_bf16(
                                      wh[nf], xh[mf], acc[mf][nf], 0, 0, 0);
                    acc[mf][nf] = __builtin_amdgcn_mfma_f32_16x16x32_bf16(
                                      wh[nf], xl[mf], acc[mf][nf], 0, 0, 0);
                    acc[mf][nf] = __builtin_amdgcn_mfma_f32_16x16x32_bf16(
                                      wl[nf], xh[mf], acc[mf][nf], 0, 0, 0);
                }
        }

        // ---- store: pixel = row0+wm*64+mf*16+lr, chan = wn*64+nf*16+cA*4+r
#pragma unroll
        for (int mf = 0; mf < 4; ++mf) {
            const size_t pix = row0 + wm * 64 + mf * 16 + lr;
#pragma unroll
            for (int nf = 0; nf < 4; ++nf) {
                const int chan = wn * 64 + nf * 16 + cA * 4;
                const f32x4 o = acc[mf][nf];
                if (tok1) {
                    const u32x2 pk = (u32x2){ pack2(o[0], o[1]), pack2(o[2], o[3]) };
                    if (nt == 0) *(u32x2*)(qb + pix * 128 + chan) = pk;
                    else         *(u32x2*)(kvb + pix * 256 + (nt - 1) * 128 + chan) = pk;
                } else {
                    const float4 bv = *(const float4*)(bias + chan);
                    f32x4 r = o;
                    r[0] += bv.x; r[1] += bv.y; r[2] += bv.z; r[3] += bv.w;
                    *(f32x4*)(outf + pix * 128 + chan) = r;
                }
            }
        }
    }
}

// ---------------------------------------------------------------------------
// MFMA halo attention. grid(256 spatial, 4 batch, 8 head), 256 thr = 4 waves.
// Wave w owns queries w*16..w*16+15 of its block's head. QK (swapped):
// S^T = K·Q^T via mfma_f32_16x16x32_bf16 (d=16 zero-padded); C-frag
// (col=q=l&15, row=key=(l>>4)*4+r) == B-frag of the 16x16x16 PV mfma.
__global__ __launch_bounds__(256) void halo_attn(
    float* out,                           // d_out fp32 (65536 x 128)
    const ushort* __restrict__ qg,        // ws q bf16 (65536 x 128)
    const ushort* __restrict__ kvg,       // ws kv bf16 (65536 x 256): h: k h*32, v h*32+16
    const float* __restrict__ pos_table)  // (729, 8)
{
    __shared__ ushort VT[16][216];        // [dim][key] bf16 (pad 208->216)  6912 B
    __shared__ float  bias_l[441];        // bias * log2e
    __shared__ int    keyoff[208];        // byte offset into kv (0 if invalid)
    __shared__ float  kmask[208];         // 0 valid / -1000 masked
    __shared__ short  koff2[208];         // ky*21+kx

    const int t  = threadIdx.x;
    const int bi = blockIdx.x, b = blockIdx.y, head = blockIdx.z;
    const int by = bi >> 4, bx = bi & 15;
    const int w  = t >> 6;                 // wave id = q-tile
    const int l  = t & 63;
    const int lr = l & 15;
    const int cA = l >> 4;

    const char* kvb = (const char*)kvg + (size_t)b * (128 * 128 * 256 * 2);

    // ---- per-block LUTs
    if (t < 208) {
        const int wy = t / 14, wx = t - (t / 14) * 14;
        const int py = by * 8 + wy - 3, px = bx * 8 + wx - 3;
        const bool valid = (t < 196) && ((unsigned)py < 128u) && ((unsigned)px < 128u);
        keyoff[t] = valid ? ((py * 128 + px) * 512) : 0;
        kmask[t]  = valid ? 0.f : -1000.f;
        koff2[t]  = (t < 196) ? (short)(wy * 21 + wx) : (short)0;
    }
    for (int i = t; i < 441; i += 256) {
        const int ry = i / 21, rx = i - ry * 21;
        bias_l[i] = pos_table[((ry + 3) * 27 + rx + 3) * 8 + head] * 1.44269504f;
    }
    __syncthreads();

    // ---- stage V^T for this head (threads 0..103, 2 keys each)
    if (t < 104) {
        const char* base = kvb + head * 64 + 32;
        const char* s0 = base + keyoff[2 * t];
        const char* s1 = base + keyoff[2 * t + 1];
        const s16x8 a0 = *(const s16x8*)s0;
        const s16x8 a1 = *(const s16x8*)(s0 + 16);
        const s16x8 c0 = *(const s16x8*)s1;
        const s16x8 c1 = *(const s16x8*)(s1 + 16);
#pragma unroll
        for (int j = 0; j < 8; ++j) {
            *(unsigned*)&VT[j][2 * t]     = ((unsigned)(ushort)c0[j] << 16) | (ushort)a0[j];
            *(unsigned*)&VT[j + 8][2 * t] = ((unsigned)(ushort)c1[j] << 16) | (ushort)a1[j];
        }
    }
    __syncthreads();

    // ---- per-wave setup: q = w*16 + lr
    const int q  = w * 16 + lr;
    const int qy = q >> 3, qx = q & 7;
    const size_t pix = ((size_t)(b * 128 + by * 8 + qy)) * 128 + bx * 8 + qx;
    float* optr = out + pix * 128 + head * 16 + cA * 4;
    const int qoff2 = (qy + 13) * 21 + (qx + 13);

    s16x8 qf;
#pragma unroll
    for (int j = 0; j < 8; ++j) qf[j] = 0;
    if (cA < 2)
        qf = *(const s16x8*)(qg + pix * 128 + head * 16 + cA * 8);

    f32x4 accv = (f32x4){0.f, 0.f, 0.f, 0.f};
    float sumf = 0.f;

#pragma unroll 1
    for (int kt = 0; kt < 13; ++kt) {
        s16x8 ak;
#pragma unroll
        for (int j = 0; j < 8; ++j) ak[j] = 0;
        if (cA < 2)
            ak = *(const s16x8*)(kvb + keyoff[kt * 16 + lr] + head * 64 + cA * 16);

        f32x4 sf = __builtin_amdgcn_mfma_f32_16x16x32_bf16(
                       ak, qf, (f32x4){0.f, 0.f, 0.f, 0.f}, 0, 0, 0);

        const int kb = kt * 16 + cA * 4;
        const s16x4 kk = *(const s16x4*)&koff2[kb];
        const f32x4 km = *(const f32x4*)&kmask[kb];
        const s16x4 vt = *(const s16x4*)&VT[lr][kb];

        float pr[4];
#pragma unroll
        for (int r = 0; r < 4; ++r) {
            const int idx = qoff2 - (int)kk[r];
            const float arg = fmaf(sf[r], 0.36067376f, bias_l[idx] + km[r]);
            pr[r] = exp2f(arg);
        }
        sumf += (pr[0] + pr[1]) + (pr[2] + pr[3]);

        s16x4 pb;
        pb[0] = (short)f2bf(pr[0]); pb[1] = (short)f2bf(pr[1]);
        pb[2] = (short)f2bf(pr[2]); pb[3] = (short)f2bf(pr[3]);
        MFMA_FENCE();
        MFMA16(accv, vt, pb);
    }
    MFMA_FENCE();

    // ---- reduce sum over cA groups (lanes lr, lr+16, lr+32, lr+48 share q)
    float s = sumf;
    s += __shfl_xor(s, 16);
    s += __shfl_xor(s, 32);
    const float inv = 1.0f / s;
    *(f32x4*)optr = accv * inv;
}

// ---------------------------------------------------------------------------
extern "C" void kernel_launch(void* const* d_in, const int* in_sizes, int n_in,
                              void* d_out, int out_size, void* d_ws, size_t ws_size,
                              hipStream_t stream) {
    const float* x      = (const float*)d_in[0];
    const float* q_w    = (const float*)d_in[1];
    const float* kv_w   = (const float*)d_in[2];
    const float* pt     = (const float*)d_in[3];
    const float* proj_w = (const float*)d_in[4];
    const float* proj_b = (const float*)d_in[5];
    float* out = (float*)d_out;

    ushort* ykvb = (ushort*)d_ws;                                   // 32 MB
    ushort* qb   = (ushort*)((char*)d_ws + 33554432);               // 16 MB
    ushort* whi  = (ushort*)((char*)d_ws + 33554432 + 16777216);    // 128 KB
    ushort* wlo  = whi + 65536;                                     // 128 KB

    const dim3 blk(256);
    conv_w<<<dim3(256), blk, 0, stream>>>(q_w, kv_w, proj_w, whi, wlo);
    gemm_split<<<dim3(512), blk, 0, stream>>>(x, whi, wlo, 0, 3, 1,
                                              qb, ykvb, nullptr, nullptr);
    halo_attn<<<dim3(256, 4, 8), blk, 0, stream>>>(out, qb, ykvb, pt);
    gemm_split<<<dim3(512), blk, 0, stream>>>(out, whi, wlo, 384, 1, 0,
                                              nullptr, nullptr, out, proj_b);
}